// Round 3
// baseline (10373.935 us; speedup 1.0000x reference)
//
#include <hip/hip_runtime.h>
#include <stdint.h>

#define Bsz  128
#define NUMS 128
#define SEQn 256
#define Hn   1024
#define PRED 96
#define G4H  4096

typedef __attribute__((ext_vector_type(8))) short bf16x8;
typedef __attribute__((ext_vector_type(4))) float f32x4;

union SMu {
  unsigned short a[2][32*512];   // double-buffered A chunks (64 KB)
  float e[4*32*18];              // epilogue exchange (aliased)
};

__device__ __forceinline__ unsigned short f2bf(float x){
  union { float f; unsigned u; } v; v.f = x;
  return (unsigned short)((v.u + 0x7FFFu + ((v.u >> 16) & 1u)) >> 16);
}

// ---- pack x: [B][NUMS][SEQ] f32 -> xp [SEQ][B][NUMS] bf16 ----
__global__ void pack_x_kernel(const float* __restrict__ x, unsigned short* __restrict__ xp){
  __shared__ float tile[64][65];
  const int t0 = blockIdx.x * 64, n0 = blockIdx.y * 64, b = blockIdx.z;
  const int tid = threadIdx.x;
  const int c = tid & 63, r = tid >> 6;
  #pragma unroll
  for (int i = 0; i < 16; i++){
    int n = r + i*4;
    tile[n][c] = x[((size_t)b*NUMS + n0 + n)*SEQn + t0 + c];
  }
  __syncthreads();
  #pragma unroll
  for (int i = 0; i < 16; i++){
    int t = r + i*4;
    xp[((size_t)(t0+t)*Bsz + b)*NUMS + n0 + c] = f2bf(tile[c][t]);
  }
}

// ---- pack W rows into MFMA B-frag order: cgg=nb*4+gate, col=gate*Hn+nb*16+(lane&15)
__global__ void pack_w_kernel(const float* __restrict__ W, unsigned short* __restrict__ Wpk,
                              int KST){
  const int u = blockIdx.x * blockDim.x + threadIdx.x;
  if (u >= 256*KST*64) return;
  const int lane = u & 63;
  const int kst  = (u >> 6) % KST;
  const int cgg  = (u >> 6) / KST;
  const int nb = cgg >> 2, gate = cgg & 3;
  const int col = gate*Hn + nb*16 + (lane & 15);
  const int kbase = kst*32 + (lane >> 4)*8;
  unsigned short tmp[8];
  #pragma unroll
  for (int e = 0; e < 8; e++) tmp[e] = f2bf(W[(size_t)(kbase+e)*G4H + col]);
  ((ulonglong2*)Wpk)[u] = *(const ulonglong2*)tmp;
}

__global__ void zero_kernel(unsigned short* __restrict__ h0, float* __restrict__ c,
                            unsigned int* __restrict__ ctr){
  int i = blockIdx.x*256 + threadIdx.x;
  if (i < Bsz*Hn){ h0[i] = 0; c[i] = 0.0f; }
  if (i < 256) ctr[i] = 0;
}

// ---- one timestep's GEMM + gates, executed inside the persistent kernel ----
template<int K1, int KTOT>
__device__ __forceinline__ void step_body(
    SMu* sm, const unsigned short* __restrict__ A1, const unsigned short* __restrict__ A2,
    const unsigned short* __restrict__ Wpk, const float* __restrict__ bias,
    float* __restrict__ cst, unsigned short* __restrict__ hout, float* __restrict__ hf_out,
    int mb, int nb, int w, int l, int tid)
{
  constexpr int KST_TOT = KTOT/32;
  constexpr int NCH = (KTOT + 511)/512;
  const int mf = w & 1, cgi = w >> 1;
  const int cgg = nb*4 + cgi;
  const int lrow = l & 15, lg = l >> 4;
  f32x4 acc = {0.f, 0.f, 0.f, 0.f};

  auto stage = [&](int bb, int ch, int kw, int lu){
    const int nissue = kw >> 4;
    for (int i = w; i < nissue; i += 8){
      const int sIdx = i*64 + l;
      const int row = sIdx >> lu;
      const int uu  = sIdx & ((1 << lu) - 1);
      const int ku  = uu ^ (row & 7);
      const int kg  = ch*512 + ku*8;
      const int R   = mb*32 + row;
      const unsigned short* src = (kg < K1) ? (A1 + (size_t)R*K1 + kg)
                                            : (A2 + (size_t)R*Hn + (kg - K1));
      __builtin_amdgcn_global_load_lds(
        (const __attribute__((address_space(1))) void*)src,
        (__attribute__((address_space(3))) void*)&sm->a[bb][i*512], 16, 0, 0);
    }
  };

  {
    constexpr int kw0 = (KTOT >= 512) ? 512 : KTOT;
    stage(0, 0, kw0, (kw0 == 512) ? 6 : 4);
  }
  __syncthreads();

  #pragma unroll
  for (int ch = 0; ch < NCH; ch++){
    const int bb = ch & 1;
    const int kw = ((KTOT - ch*512) >= 512) ? 512 : (KTOT - ch*512);
    if (ch + 1 < NCH){
      const int kwn = ((KTOT - (ch+1)*512) >= 512) ? 512 : (KTOT - (ch+1)*512);
      stage(bb ^ 1, ch+1, kwn, (kwn == 512) ? 6 : 4);
    }
    const int UPR  = kw >> 3;
    const int kstc = kw >> 5;
    const int row  = mf*16 + lrow;
    const unsigned short* wp = Wpk + ((size_t)(cgg*KST_TOT + ch*16)*64 + l)*8;
    #pragma unroll
    for (int ks = 0; ks < kstc; ks++){
      const int unit = ks*4 + lg;
      bf16x8 af = *(const bf16x8*)&sm->a[bb][(row*UPR + (unit ^ (row & 7)))*8];
      bf16x8 bw = *(const bf16x8*)(wp + (size_t)ks*512);
      acc = __builtin_amdgcn_mfma_f32_16x16x32_bf16(af, bw, acc, 0, 0, 0);
    }
    __syncthreads();
  }

  {
    const int jj = l & 15;
    #pragma unroll
    for (int r = 0; r < 4; r++){
      const int row = mf*16 + lg*4 + r;
      sm->e[(cgi*32 + row)*18 + jj] = acc[r];
    }
  }
  __syncthreads();
  {
    const int row = tid >> 4, jj = tid & 15;
    const int R = mb*32 + row;
    const int J = nb*16 + jj;
    const float zi = sm->e[(0*32+row)*18 + jj] + bias[0*Hn + J];
    const float zf = sm->e[(1*32+row)*18 + jj] + bias[1*Hn + J];
    const float zo = sm->e[(2*32+row)*18 + jj] + bias[2*Hn + J];
    const float zg = sm->e[(3*32+row)*18 + jj] + bias[3*Hn + J];
    const float gi = 1.f/(1.f + __expf(-zi));
    const float gf = 1.f/(1.f + __expf(-zf));
    const float go = 1.f/(1.f + __expf(-zo));
    const float gg = tanhf(zg);
    const size_t idx = (size_t)R*Hn + J;
    const float cn = gf * cst[idx] + gi * gg;
    cst[idx] = cn;
    const float hn = go * tanhf(cn);
    hout[idx] = f2bf(hn);
    if (hf_out) hf_out[idx] = hn;
  }
  __syncthreads();   // protect sm reuse (next step stages into sm->a)
}

// ---- persistent kernel: all 512 timesteps, mb-group barriers between steps ----
__global__ __launch_bounds__(512, 2)
void lstm_persist(const unsigned short* __restrict__ xp,
                  unsigned short* __restrict__ H0,
                  unsigned short* __restrict__ H1,
                  const unsigned short* __restrict__ Wpk0,
                  const unsigned short* __restrict__ Wpk1,
                  const float* __restrict__ b0, const float* __restrict__ b1,
                  float* __restrict__ cst, float* __restrict__ hf,
                  unsigned int* __restrict__ ctr, int h1_slots)
{
  __shared__ SMu sm;
  const int tid = threadIdx.x, w = tid >> 6, l = tid & 63;
  const int blk = blockIdx.x;
  const int q = blk >> 3;
  const int nb = (blk & 7)*8 + (q & 7);   // XCD-local W slice
  const int mb = q >> 3;
  unsigned int* cmb = ctr + mb*64;        // 256 B apart

  auto wait_phase = [&](unsigned target){
    if (tid == 0){
      while (__hip_atomic_load(cmb, __ATOMIC_RELAXED, __HIP_MEMORY_SCOPE_AGENT) < target)
        __builtin_amdgcn_s_sleep(2);
    }
    __syncthreads();
    __builtin_amdgcn_fence(__ATOMIC_ACQUIRE, "workgroup");  // compiler barrier
  };
  auto arrive = [&](){
    __syncthreads();   // all threads' stores issued (+vmcnt drained at barrier)
    if (tid == 0){
      __builtin_amdgcn_fence(__ATOMIC_RELEASE, "agent");    // L2 writeback, no inv
      __hip_atomic_fetch_add(cmb, 1u, __ATOMIC_RELAXED, __HIP_MEMORY_SCOPE_AGENT);
    }
  };

  // layer 0: A = [x_t | h_prev], h ring H0 slot t -> t+1
  for (int t = 0; t < SEQn; t++){
    if (t) wait_phase(64u*(unsigned)t);
    step_body<NUMS, NUMS+Hn>(&sm,
        xp + (size_t)t*Bsz*NUMS,
        H0 + (size_t)t*Bsz*Hn,
        Wpk0, b0, cst,
        H0 + (size_t)(t+1)*Bsz*Hn, nullptr,
        mb, nb, w, l, tid);
    arrive();
  }
  // layer 1: A = [h0_t | h_prev]
  for (int t = 0; t < SEQn; t++){
    wait_phase(64u*(unsigned)(SEQn + t));
    if (h1_slots != SEQn) __threadfence();  // reused-slot coherence fallback
    const unsigned short* A2 = (t == 0) ? (H0 + (size_t)SEQn*Bsz*Hn)
                                        : (H1 + (size_t)((t-1) % h1_slots)*Bsz*Hn);
    step_body<Hn, 2*Hn>(&sm,
        H0 + (size_t)(t+1)*Bsz*Hn,
        A2,
        Wpk1, b1, cst,
        H1 + (size_t)(t % h1_slots)*Bsz*Hn,
        (t == SEQn-1) ? hf : nullptr,
        mb, nb, w, l, tid);
    arrive();
  }
}

// ---- final FC + copy h,c to d_out ----
__global__ __launch_bounds__(256)
void fc_out_kernel(const float* __restrict__ hf, const float* __restrict__ cst,
                   const float* __restrict__ fcw, const float* __restrict__ fcb,
                   float* __restrict__ dout){
  __shared__ float hrow[Hn];
  const int b = blockIdx.x, tid = threadIdx.x;
  for (int i = tid; i < Hn; i += 256) hrow[i] = hf[(size_t)b*Hn + i];
  __syncthreads();
  if (tid < PRED){
    float a = fcb[tid];
    for (int k = 0; k < Hn; k++) a += hrow[k] * fcw[(size_t)k*PRED + tid];
    dout[(size_t)b*PRED + tid] = tanhf(a);
  }
  for (int i = tid; i < Hn; i += 256){
    dout[Bsz*PRED + (size_t)b*Hn + i] = hf[(size_t)b*Hn + i];
    dout[Bsz*PRED + (size_t)Bsz*Hn + (size_t)b*Hn + i] = cst[(size_t)b*Hn + i];
  }
}

extern "C" void kernel_launch(void* const* d_in, const int* in_sizes, int n_in,
                              void* d_out, int out_size, void* d_ws, size_t ws_size,
                              hipStream_t stream){
  const float* x   = (const float*)d_in[0];
  const float* W0  = (const float*)d_in[1];
  const float* b0  = (const float*)d_in[2];
  const float* W1  = (const float*)d_in[3];
  const float* b1  = (const float*)d_in[4];
  const float* fcw = (const float*)d_in[5];
  const float* fcb = (const float*)d_in[6];
  float* dout = (float*)d_out;

  char* p = (char*)d_ws;
  auto alloc = [&](size_t bytes)->void*{
    void* r = (void*)p; p += (bytes + 255) & ~(size_t)255; return r;
  };
  unsigned short* xp   = (unsigned short*)alloc((size_t)SEQn*Bsz*NUMS*2);      // 8.4 MB
  unsigned short* Wpk0 = (unsigned short*)alloc((size_t)256*36*64*8*2);        // 9.4 MB
  unsigned short* Wpk1 = (unsigned short*)alloc((size_t)256*64*64*8*2);        // 16.8 MB
  unsigned short* H0   = (unsigned short*)alloc((size_t)(SEQn+1)*Bsz*Hn*2);    // 67.4 MB
  float* cst = (float*)alloc((size_t)Bsz*Hn*4);
  float* hf  = (float*)alloc((size_t)Bsz*Hn*4);
  unsigned int* ctr = (unsigned int*)alloc(256*4);

  // layer-1 h ring: linear (no address reuse -> no stale-cache hazard) if ws allows
  const size_t base_used = (size_t)(p - (char*)d_ws);
  const bool lin = (ws_size >= base_used + (size_t)SEQn*Bsz*Hn*2 + (1u<<20));
  const int h1_slots = lin ? SEQn : 4;
  unsigned short* H1 = (unsigned short*)alloc((size_t)h1_slots*Bsz*Hn*2);

  pack_x_kernel<<<dim3(SEQn/64, NUMS/64, Bsz), dim3(256), 0, stream>>>(x, xp);
  pack_w_kernel<<<dim3((256*36*64 + 255)/256), dim3(256), 0, stream>>>(W0, Wpk0, 36);
  pack_w_kernel<<<dim3((256*64*64 + 255)/256), dim3(256), 0, stream>>>(W1, Wpk1, 64);
  zero_kernel<<<dim3((Bsz*Hn + 255)/256), dim3(256), 0, stream>>>(H0, cst, ctr);

  lstm_persist<<<dim3(256), dim3(512), 0, stream>>>(
      xp, H0, H1, Wpk0, Wpk1, b0, b1, cst, hf, ctr, h1_slots);

  fc_out_kernel<<<dim3(Bsz), dim3(256), 0, stream>>>(hf, cst, fcw, fcb, dout);
}

// Round 4
// 9424.036 us; speedup vs baseline: 1.1008x; 1.1008x over previous
//
#include <hip/hip_runtime.h>
#include <stdint.h>

#define Bsz  128
#define NUMS 128
#define SEQn 256
#define Hn   1024
#define PRED 96
#define G4H  4096

typedef __attribute__((ext_vector_type(8))) short bf16x8;
typedef __attribute__((ext_vector_type(4))) float f32x4;

union SMu {
  unsigned short a[2][32*512];   // double-buffered A chunks (64 KB)
  float e[4*32*18];              // epilogue exchange (aliases a[0] head)
};

__device__ __forceinline__ unsigned short f2bf(float x){
  union { float f; unsigned u; } v; v.f = x;
  return (unsigned short)((v.u + 0x7FFFu + ((v.u >> 16) & 1u)) >> 16);
}

// ---- pack x: [B][NUMS][SEQ] f32 -> xp [SEQ][B][NUMS] bf16 ----
__global__ void pack_x_kernel(const float* __restrict__ x, unsigned short* __restrict__ xp){
  __shared__ float tile[64][65];
  const int t0 = blockIdx.x * 64, n0 = blockIdx.y * 64, b = blockIdx.z;
  const int tid = threadIdx.x;
  const int c = tid & 63, r = tid >> 6;
  #pragma unroll
  for (int i = 0; i < 16; i++){
    int n = r + i*4;
    tile[n][c] = x[((size_t)b*NUMS + n0 + n)*SEQn + t0 + c];
  }
  __syncthreads();
  #pragma unroll
  for (int i = 0; i < 16; i++){
    int t = r + i*4;
    xp[((size_t)(t0+t)*Bsz + b)*NUMS + n0 + c] = f2bf(tile[c][t]);
  }
}

// ---- pack W rows into MFMA B-frag order: cgg=nb*4+gate, col=gate*Hn+nb*16+(lane&15)
__global__ void pack_w_kernel(const float* __restrict__ W, unsigned short* __restrict__ Wpk,
                              int KST){
  const int u = blockIdx.x * blockDim.x + threadIdx.x;
  if (u >= 256*KST*64) return;
  const int lane = u & 63;
  const int kst  = (u >> 6) % KST;
  const int cgg  = (u >> 6) / KST;
  const int nb = cgg >> 2, gate = cgg & 3;
  const int col = gate*Hn + nb*16 + (lane & 15);
  const int kbase = kst*32 + (lane >> 4)*8;
  unsigned short tmp[8];
  #pragma unroll
  for (int e = 0; e < 8; e++) tmp[e] = f2bf(W[(size_t)(kbase+e)*G4H + col]);
  ((ulonglong2*)Wpk)[u] = *(const ulonglong2*)tmp;
}

__global__ void zero_kernel(unsigned short* __restrict__ h0, float* __restrict__ c,
                            unsigned int* __restrict__ ctr){
  int i = blockIdx.x*256 + threadIdx.x;
  if (i < Bsz*Hn){ h0[i] = 0; c[i] = 0.0f; }
  if (i < 256) ctr[i] = 0;
}

// ---- layer-0 timestep body (A addresses all write-once; normal cached path) ----
template<int K1, int KTOT>
__device__ __forceinline__ void step_body(
    SMu* sm, const unsigned short* __restrict__ A1, const unsigned short* __restrict__ A2,
    const unsigned short* __restrict__ Wpk, const float* __restrict__ bias,
    float* __restrict__ cst, unsigned short* __restrict__ hout,
    int mb, int nb, int w, int l, int tid)
{
  constexpr int KST_TOT = KTOT/32;
  constexpr int NCH = (KTOT + 511)/512;
  const int mf = w & 1, cgi = w >> 1;
  const int cgg = nb*4 + cgi;
  const int lrow = l & 15, lg = l >> 4;
  f32x4 acc = {0.f, 0.f, 0.f, 0.f};

  auto stage = [&](int bb, int ch, int kw, int lu){
    const int nissue = kw >> 4;
    for (int i = w; i < nissue; i += 8){
      const int sIdx = i*64 + l;
      const int row = sIdx >> lu;
      const int uu  = sIdx & ((1 << lu) - 1);
      const int ku  = uu ^ (row & 7);
      const int kg  = ch*512 + ku*8;
      const int R   = mb*32 + row;
      const unsigned short* src = (kg < K1) ? (A1 + (size_t)R*K1 + kg)
                                            : (A2 + (size_t)R*Hn + (kg - K1));
      __builtin_amdgcn_global_load_lds(
        (const __attribute__((address_space(1))) void*)src,
        (__attribute__((address_space(3))) void*)&sm->a[bb][i*512], 16, 0, 0);
    }
  };

  {
    constexpr int kw0 = (KTOT >= 512) ? 512 : KTOT;
    stage(0, 0, kw0, (kw0 == 512) ? 6 : 4);
  }
  __syncthreads();

  #pragma unroll
  for (int ch = 0; ch < NCH; ch++){
    const int bb = ch & 1;
    const int kw = ((KTOT - ch*512) >= 512) ? 512 : (KTOT - ch*512);
    if (ch + 1 < NCH){
      const int kwn = ((KTOT - (ch+1)*512) >= 512) ? 512 : (KTOT - (ch+1)*512);
      stage(bb ^ 1, ch+1, kwn, (kwn == 512) ? 6 : 4);
    }
    const int UPR  = kw >> 3;
    const int kstc = kw >> 5;
    const int row  = mf*16 + lrow;
    const unsigned short* wp = Wpk + ((size_t)(cgg*KST_TOT + ch*16)*64 + l)*8;
    #pragma unroll
    for (int ks = 0; ks < kstc; ks++){
      const int unit = ks*4 + lg;
      bf16x8 af = *(const bf16x8*)&sm->a[bb][(row*UPR + (unit ^ (row & 7)))*8];
      bf16x8 bw = *(const bf16x8*)(wp + (size_t)ks*512);
      acc = __builtin_amdgcn_mfma_f32_16x16x32_bf16(af, bw, acc, 0, 0, 0);
    }
    __syncthreads();
  }

  {
    const int jj = l & 15;
    #pragma unroll
    for (int r = 0; r < 4; r++){
      const int row = mf*16 + lg*4 + r;
      sm->e[(cgi*32 + row)*18 + jj] = acc[r];
    }
  }
  __syncthreads();
  {
    const int row = tid >> 4, jj = tid & 15;
    const int R = mb*32 + row;
    const int J = nb*16 + jj;
    const float zi = sm->e[(0*32+row)*18 + jj] + bias[0*Hn + J];
    const float zf = sm->e[(1*32+row)*18 + jj] + bias[1*Hn + J];
    const float zo = sm->e[(2*32+row)*18 + jj] + bias[2*Hn + J];
    const float zg = sm->e[(3*32+row)*18 + jj] + bias[3*Hn + J];
    const float gi = 1.f/(1.f + __expf(-zi));
    const float gf = 1.f/(1.f + __expf(-zf));
    const float go = 1.f/(1.f + __expf(-zo));
    const float gg = tanhf(zg);
    const size_t idx = (size_t)R*Hn + J;
    const float cn = gf * cst[idx] + gi * gg;
    cst[idx] = cn;
    const float hn = go * tanhf(cn);
    hout[idx] = f2bf(hn);
  }
}

// ---- persistent kernel: 512 timesteps; mb-group barriers; no agent-acquire ever ----
__global__ __launch_bounds__(512, 1)
void lstm_persist(const unsigned short* __restrict__ xp,
                  unsigned short* __restrict__ H0,
                  unsigned short* __restrict__ H1,
                  const unsigned short* __restrict__ Wpk0,
                  const unsigned short* __restrict__ Wpk1,
                  const float* __restrict__ b0, const float* __restrict__ b1,
                  float* __restrict__ cst, float* __restrict__ hf,
                  unsigned int* __restrict__ ctr)
{
  __shared__ SMu sm;
  const int tid = threadIdx.x, w = tid >> 6, l = tid & 63;
  const int blk = blockIdx.x;
  const int q = blk >> 3;
  const int nb = (blk & 7)*8 + (q & 7);   // XCD-local W slice
  const int mb = q >> 3;
  unsigned int* cmb = ctr + mb*64;

  auto wait_phase = [&](unsigned target){
    if (tid == 0){
      while (__hip_atomic_load(cmb, __ATOMIC_RELAXED, __HIP_MEMORY_SCOPE_AGENT) < target)
        __builtin_amdgcn_s_sleep(2);
    }
    __syncthreads();                                        // also drains vmcnt (pre-staged LDS)
    __builtin_amdgcn_fence(__ATOMIC_ACQUIRE, "workgroup");  // compiler barrier only
  };
  auto arrive = [&](){
    __syncthreads();
    if (tid == 0){
      __builtin_amdgcn_fence(__ATOMIC_RELEASE, "agent");    // L2 writeback (dirty ~3 KB/block)
      __hip_atomic_fetch_add(cmb, 1u, __ATOMIC_RELAXED, __HIP_MEMORY_SCOPE_AGENT);
    }
  };

  // ---------------- layer 0: A = [x_t | h0_prev], H0 ring slot t -> t+1 ----------------
  for (int t = 0; t < SEQn; t++){
    if (t) wait_phase(64u*(unsigned)t);
    step_body<NUMS, NUMS+Hn>(&sm,
        xp + (size_t)t*Bsz*NUMS,
        H0 + (size_t)t*Bsz*Hn,
        Wpk0, b0, cst,
        H0 + (size_t)(t+1)*Bsz*Hn,
        mb, nb, w, l, tid);
    arrive();
  }

  // ---------------- layer 1: A = [h0_t | h1_prev], pipelined ----------------
  const int mf = w & 1, cgi = w >> 1;
  const int cgg = nb*4 + cgi;
  const int lrow = l & 15, lg = l >> 4;
  const int frow = mf*16 + lrow;

  for (int t = 0; t < SEQn; t++){
    const unsigned short* A1 = H0 + (size_t)(t+1)*Bsz*Hn;         // h0_t (write-once)
    const unsigned short* A2 = (t == 0) ? (H0 + (size_t)SEQn*Bsz*Hn)
                                        : (H1 + (size_t)((t-1)&1)*Bsz*Hn);
    // pre-stage A1 chunks 0,1 (k 0..1023) during barrier spin — data ready since layer-0 done
    #pragma unroll
    for (int c = 0; c < 2; c++){
      for (int i = w; i < 32; i += 8){
        const int sIdx = i*64 + l;
        const int row = sIdx >> 6, uu = sIdx & 63, ku = uu ^ (row & 7);
        const unsigned short* src = A1 + (size_t)(mb*32 + row)*Hn + c*512 + ku*8;
        __builtin_amdgcn_global_load_lds(
          (const __attribute__((address_space(1))) void*)src,
          (__attribute__((address_space(3))) void*)&sm.a[c][i*512], 16, 0, 0);
      }
    }
    wait_phase(64u*(unsigned)(SEQn + t));    // h1_{t-1} published (writer wb'd to L3)

    // coherent (L2-bypassing) loads of A2 = h1_prev (k 1024..2047) into registers
    unsigned long long rg[2][4][2];
    #pragma unroll
    for (int c = 0; c < 2; c++)
      #pragma unroll
      for (int j = 0; j < 4; j++){
        const int sIdx = j*512 + tid;
        const int row = sIdx >> 6, uu = sIdx & 63, ku = uu ^ (row & 7);
        const unsigned long long* qp = (const unsigned long long*)A2
            + ((size_t)(mb*32 + row)*Hn + c*512 + ku*8)/4;
        rg[c][j][0] = __hip_atomic_load(qp,   __ATOMIC_RELAXED, __HIP_MEMORY_SCOPE_AGENT);
        rg[c][j][1] = __hip_atomic_load(qp+1, __ATOMIC_RELAXED, __HIP_MEMORY_SCOPE_AGENT);
      }

    f32x4 acc = {0.f, 0.f, 0.f, 0.f};
    // MFMA chunks 0,1 (overlaps atomic-load latency)
    #pragma unroll
    for (int c = 0; c < 2; c++){
      const unsigned short* wp = Wpk1 + ((size_t)(cgg*64 + c*16)*64 + l)*8;
      #pragma unroll
      for (int ks = 0; ks < 16; ks++){
        const int unit = ks*4 + lg;
        bf16x8 af = *(const bf16x8*)&sm.a[c][(frow*64 + (unit ^ (frow & 7)))*8];
        bf16x8 bw = *(const bf16x8*)(wp + (size_t)ks*512);
        acc = __builtin_amdgcn_mfma_f32_16x16x32_bf16(af, bw, acc, 0, 0, 0);
      }
    }
    __syncthreads();                         // chunks 0,1 fully consumed; buffers free
    #pragma unroll
    for (int c = 0; c < 2; c++)
      #pragma unroll
      for (int j = 0; j < 4; j++){
        ulonglong2 v; v.x = rg[c][j][0]; v.y = rg[c][j][1];
        *(ulonglong2*)&sm.a[c][(j*512 + tid)*8] = v;
      }
    __syncthreads();                         // A2 chunks staged
    // MFMA chunks 2,3
    #pragma unroll
    for (int c = 0; c < 2; c++){
      const unsigned short* wp = Wpk1 + ((size_t)(cgg*64 + (2+c)*16)*64 + l)*8;
      #pragma unroll
      for (int ks = 0; ks < 16; ks++){
        const int unit = ks*4 + lg;
        bf16x8 af = *(const bf16x8*)&sm.a[c][(frow*64 + (unit ^ (frow & 7)))*8];
        bf16x8 bw = *(const bf16x8*)(wp + (size_t)ks*512);
        acc = __builtin_amdgcn_mfma_f32_16x16x32_bf16(af, bw, acc, 0, 0, 0);
      }
    }
    __syncthreads();                         // all reads of sm.a done before e-alias write

    {
      const int jj = l & 15;
      #pragma unroll
      for (int r = 0; r < 4; r++){
        const int row = mf*16 + lg*4 + r;
        sm.e[(cgi*32 + row)*18 + jj] = acc[r];
      }
    }
    __syncthreads();
    {
      const int row = tid >> 4, jj = tid & 15;
      const int R = mb*32 + row;
      const int J = nb*16 + jj;
      const float zi = sm.e[(0*32+row)*18 + jj] + b1[0*Hn + J];
      const float zf = sm.e[(1*32+row)*18 + jj] + b1[1*Hn + J];
      const float zo = sm.e[(2*32+row)*18 + jj] + b1[2*Hn + J];
      const float zg = sm.e[(3*32+row)*18 + jj] + b1[3*Hn + J];
      const float gi = 1.f/(1.f + __expf(-zi));
      const float gf = 1.f/(1.f + __expf(-zf));
      const float go = 1.f/(1.f + __expf(-zo));
      const float gg = tanhf(zg);
      const size_t idx = (size_t)R*Hn + J;
      const float cn = gf * cst[idx] + gi * gg;
      cst[idx] = cn;
      const float hn = go * tanhf(cn);
      H1[(size_t)(t & 1)*Bsz*Hn + idx] = f2bf(hn);
      if (t == SEQn-1) hf[idx] = hn;
    }
    arrive();
  }
}

// ---- final FC + copy h,c to d_out ----
__global__ __launch_bounds__(256)
void fc_out_kernel(const float* __restrict__ hf, const float* __restrict__ cst,
                   const float* __restrict__ fcw, const float* __restrict__ fcb,
                   float* __restrict__ dout){
  __shared__ float hrow[Hn];
  const int b = blockIdx.x, tid = threadIdx.x;
  for (int i = tid; i < Hn; i += 256) hrow[i] = hf[(size_t)b*Hn + i];
  __syncthreads();
  if (tid < PRED){
    float a = fcb[tid];
    for (int k = 0; k < Hn; k++) a += hrow[k] * fcw[(size_t)k*PRED + tid];
    dout[(size_t)b*PRED + tid] = tanhf(a);
  }
  for (int i = tid; i < Hn; i += 256){
    dout[Bsz*PRED + (size_t)b*Hn + i] = hf[(size_t)b*Hn + i];
    dout[Bsz*PRED + (size_t)Bsz*Hn + (size_t)b*Hn + i] = cst[(size_t)b*Hn + i];
  }
}

extern "C" void kernel_launch(void* const* d_in, const int* in_sizes, int n_in,
                              void* d_out, int out_size, void* d_ws, size_t ws_size,
                              hipStream_t stream){
  const float* x   = (const float*)d_in[0];
  const float* W0  = (const float*)d_in[1];
  const float* b0  = (const float*)d_in[2];
  const float* W1  = (const float*)d_in[3];
  const float* b1  = (const float*)d_in[4];
  const float* fcw = (const float*)d_in[5];
  const float* fcb = (const float*)d_in[6];
  float* dout = (float*)d_out;

  char* p = (char*)d_ws;
  auto alloc = [&](size_t bytes)->void*{
    void* r = (void*)p; p += (bytes + 255) & ~(size_t)255; return r;
  };
  unsigned short* xp   = (unsigned short*)alloc((size_t)SEQn*Bsz*NUMS*2);      // 8.4 MB
  unsigned short* Wpk0 = (unsigned short*)alloc((size_t)256*36*64*8*2);        // 9.4 MB
  unsigned short* Wpk1 = (unsigned short*)alloc((size_t)256*64*64*8*2);        // 16.8 MB
  unsigned short* H0   = (unsigned short*)alloc((size_t)(SEQn+1)*Bsz*Hn*2);    // 67.4 MB
  unsigned short* H1   = (unsigned short*)alloc((size_t)2*Bsz*Hn*2);           // 0.5 MB
  float* cst = (float*)alloc((size_t)Bsz*Hn*4);
  float* hf  = (float*)alloc((size_t)Bsz*Hn*4);
  unsigned int* ctr = (unsigned int*)alloc(256*4);

  pack_x_kernel<<<dim3(SEQn/64, NUMS/64, Bsz), dim3(256), 0, stream>>>(x, xp);
  pack_w_kernel<<<dim3((256*36*64 + 255)/256), dim3(256), 0, stream>>>(W0, Wpk0, 36);
  pack_w_kernel<<<dim3((256*64*64 + 255)/256), dim3(256), 0, stream>>>(W1, Wpk1, 64);
  zero_kernel<<<dim3((Bsz*Hn + 255)/256), dim3(256), 0, stream>>>(H0, cst, ctr);

  lstm_persist<<<dim3(256), dim3(512), 0, stream>>>(
      xp, H0, H1, Wpk0, Wpk1, b0, b1, cst, hf, ctr);

  fc_out_kernel<<<dim3(Bsz), dim3(256), 0, stream>>>(hf, cst, fcw, fcb, dout);
}

// Round 5
// 6371.180 us; speedup vs baseline: 1.6283x; 1.4792x over previous
//
#include <hip/hip_runtime.h>
#include <stdint.h>

#define Bsz  128
#define NUMS 128
#define SEQn 256
#define Hn   1024
#define PRED 96
#define G4H  4096

typedef __attribute__((ext_vector_type(8))) short bf16x8;
typedef __attribute__((ext_vector_type(4))) float f32x4;

union SMu {
  unsigned short a[2][32*512];   // double-buffered A chunks (64 KB)
  float e[4*32*18];              // epilogue exchange (aliases sm.a[0] head)
};

__device__ __forceinline__ unsigned short f2bf(float x){
  union { float f; unsigned u; } v; v.f = x;
  return (unsigned short)((v.u + 0x7FFFu + ((v.u >> 16) & 1u)) >> 16);
}

// ---- pack x: [B][NUMS][SEQ] f32 -> xp [SEQ][B][NUMS] bf16 ----
__global__ void pack_x_kernel(const float* __restrict__ x, unsigned short* __restrict__ xp){
  __shared__ float tile[64][65];
  const int t0 = blockIdx.x * 64, n0 = blockIdx.y * 64, b = blockIdx.z;
  const int tid = threadIdx.x;
  const int c = tid & 63, r = tid >> 6;
  #pragma unroll
  for (int i = 0; i < 16; i++){
    int n = r + i*4;
    tile[n][c] = x[((size_t)b*NUMS + n0 + n)*SEQn + t0 + c];
  }
  __syncthreads();
  #pragma unroll
  for (int i = 0; i < 16; i++){
    int t = r + i*4;
    xp[((size_t)(t0+t)*Bsz + b)*NUMS + n0 + c] = f2bf(tile[c][t]);
  }
}

// ---- pack W rows into MFMA B-frag order: cgg=nb*4+gate, col=gate*Hn+nb*16+(lane&15)
__global__ void pack_w_kernel(const float* __restrict__ W, unsigned short* __restrict__ Wpk,
                              int KST){
  const int u = blockIdx.x * blockDim.x + threadIdx.x;
  if (u >= 256*KST*64) return;
  const int lane = u & 63;
  const int kst  = (u >> 6) % KST;
  const int cgg  = (u >> 6) / KST;
  const int nb = cgg >> 2, gate = cgg & 3;
  const int col = gate*Hn + nb*16 + (lane & 15);
  const int kbase = kst*32 + (lane >> 4)*8;
  unsigned short tmp[8];
  #pragma unroll
  for (int e = 0; e < 8; e++) tmp[e] = f2bf(W[(size_t)(kbase+e)*G4H + col]);
  ((ulonglong2*)Wpk)[u] = *(const ulonglong2*)tmp;
}

__global__ void zero_kernel(unsigned short* __restrict__ h0, float* __restrict__ c,
                            unsigned int* __restrict__ ctr){
  int i = blockIdx.x*256 + threadIdx.x;
  if (i < Bsz*Hn){ h0[i] = 0; c[i] = 0.0f; }
  if (i < 1280) ctr[i] = 0;
}

// ---- gate math + publish for a 2-column slice (threads 0..255) ----
__device__ __forceinline__ void epilogue2(
    SMu* sm, const float* __restrict__ bias, float* __restrict__ cst,
    unsigned int* __restrict__ hout32, float* __restrict__ hf_out,
    int mb, int nb, int tid)
{
  if (tid < 256){
    const int row = tid >> 3, jp = (tid & 7)*2;
    const int R = mb*32 + row, J = nb*16 + jp;
    float z[4][2];
    #pragma unroll
    for (int g = 0; g < 4; g++){
      z[g][0] = sm->e[(g*32+row)*18 + jp]     + bias[g*Hn + J];
      z[g][1] = sm->e[(g*32+row)*18 + jp + 1] + bias[g*Hn + J + 1];
    }
    const size_t idx = (size_t)R*Hn + J;
    float2 cv = *(const float2*)&cst[idx];
    float hn[2], cn[2];
    #pragma unroll
    for (int u = 0; u < 2; u++){
      const float gi = 1.f/(1.f + __expf(-z[0][u]));
      const float gf = 1.f/(1.f + __expf(-z[1][u]));
      const float go = 1.f/(1.f + __expf(-z[2][u]));
      const float gg = tanhf(z[3][u]);
      cn[u] = gf * (u ? cv.y : cv.x) + gi * gg;
      hn[u] = go * tanhf(cn[u]);
    }
    float2 cw; cw.x = cn[0]; cw.y = cn[1];
    *(float2*)&cst[idx] = cw;
    const unsigned hb = (unsigned)f2bf(hn[0]) | ((unsigned)f2bf(hn[1]) << 16);
    // write-through publish (no L2 dirty state -> no wbl2 needed anywhere)
    __hip_atomic_store(hout32 + (idx >> 1), hb, __ATOMIC_RELAXED, __HIP_MEMORY_SCOPE_AGENT);
    if (hf_out){ float2 hw; hw.x = hn[0]; hw.y = hn[1]; *(float2*)&hf_out[idx] = hw; }
  }
}

// ---- layer-0 timestep body ----
template<int K1, int KTOT>
__device__ __forceinline__ void step_body(
    SMu* sm, const unsigned short* __restrict__ A1, const unsigned short* __restrict__ A2,
    const unsigned short* __restrict__ Wpk, const float* __restrict__ bias,
    float* __restrict__ cst, unsigned int* __restrict__ hout32,
    int mb, int nb, int w, int l, int tid)
{
  constexpr int KST_TOT = KTOT/32;
  constexpr int NCH = (KTOT + 511)/512;
  const int mf = w & 1, cgi = w >> 1;
  const int cgg = nb*4 + cgi;
  const int lrow = l & 15, lg = l >> 4;
  f32x4 acc = {0.f, 0.f, 0.f, 0.f};

  auto stage = [&](int bb, int ch, int kw, int lu){
    const int nissue = kw >> 4;
    for (int i = w; i < nissue; i += 8){
      const int sIdx = i*64 + l;
      const int row = sIdx >> lu;
      const int uu  = sIdx & ((1 << lu) - 1);
      const int ku  = uu ^ (row & 7);
      const int kg  = ch*512 + ku*8;
      const int R   = mb*32 + row;
      const unsigned short* src = (kg < K1) ? (A1 + (size_t)R*K1 + kg)
                                            : (A2 + (size_t)R*Hn + (kg - K1));
      __builtin_amdgcn_global_load_lds(
        (const __attribute__((address_space(1))) void*)src,
        (__attribute__((address_space(3))) void*)&sm->a[bb][i*512], 16, 0, 0);
    }
  };

  {
    constexpr int kw0 = (KTOT >= 512) ? 512 : KTOT;
    stage(0, 0, kw0, (kw0 == 512) ? 6 : 4);
  }
  __syncthreads();

  #pragma unroll
  for (int ch = 0; ch < NCH; ch++){
    const int bb = ch & 1;
    const int kw = ((KTOT - ch*512) >= 512) ? 512 : (KTOT - ch*512);
    if (ch + 1 < NCH){
      const int kwn = ((KTOT - (ch+1)*512) >= 512) ? 512 : (KTOT - (ch+1)*512);
      stage(bb ^ 1, ch+1, kwn, (kwn == 512) ? 6 : 4);
    }
    const int UPR  = kw >> 3;
    const int kstc = kw >> 5;
    const int row  = mf*16 + lrow;
    const unsigned short* wp = Wpk + ((size_t)(cgg*KST_TOT + ch*16)*64 + l)*8;
    #pragma unroll
    for (int ks = 0; ks < kstc; ks++){
      const int unit = ks*4 + lg;
      bf16x8 af = *(const bf16x8*)&sm->a[bb][(row*UPR + (unit ^ (row & 7)))*8];
      bf16x8 bw = *(const bf16x8*)(wp + (size_t)ks*512);
      acc = __builtin_amdgcn_mfma_f32_16x16x32_bf16(af, bw, acc, 0, 0, 0);
    }
    __syncthreads();
  }

  {
    const int jj = l & 15;
    #pragma unroll
    for (int r = 0; r < 4; r++){
      const int row = mf*16 + lg*4 + r;
      sm->e[(cgi*32 + row)*18 + jj] = acc[r];
    }
  }
  __syncthreads();
  epilogue2(sm, bias, cst, hout32, nullptr, mb, nb, tid);
}

// ---- persistent kernel: hierarchical barrier, write-through h publish, no wbl2 ----
__global__ __launch_bounds__(512, 1)
void lstm_persist(const unsigned short* __restrict__ xp,
                  unsigned short* __restrict__ H0,
                  unsigned short* __restrict__ H1,
                  const unsigned short* __restrict__ Wpk0,
                  const unsigned short* __restrict__ Wpk1,
                  const float* __restrict__ b0, const float* __restrict__ b1,
                  float* __restrict__ cst, float* __restrict__ hf,
                  unsigned int* __restrict__ ctrA, unsigned int* __restrict__ gctr)
{
  __shared__ SMu sm;
  const int tid = threadIdx.x, w = tid >> 6, l = tid & 63;
  const int blk = blockIdx.x;
  const int q = blk >> 3;
  const int nb = (blk & 7)*8 + (q & 7);   // XCD-local W slice (blk&7 ~ XCD)
  const int mb = q >> 3;
  const int ga = blk & 7;                 // arrival sub-group (8 blocks each)
  unsigned int* actr = ctrA + (mb*8 + ga)*32;   // 128B-spaced lines
  unsigned int* gptr = gctr + mb*64;            // 256B-spaced lines

  auto wait_phase = [&](unsigned p){
    if (tid == 0){
      const unsigned tgt = 8u*p;
      while (__hip_atomic_load(gptr, __ATOMIC_RELAXED, __HIP_MEMORY_SCOPE_AGENT) < tgt)
        __builtin_amdgcn_s_sleep(1);
    }
    __syncthreads();
    __builtin_amdgcn_fence(__ATOMIC_ACQUIRE, "workgroup");  // compiler barrier only
  };
  auto arrive = [&](){
    __syncthreads();   // every wave drains vmcnt before barrier -> h stores complete
    if (tid == 0){
      unsigned old = __hip_atomic_fetch_add(actr, 1u, __ATOMIC_RELAXED, __HIP_MEMORY_SCOPE_AGENT);
      if ((old & 7u) == 7u)   // 8th arrival of this phase in this sub-group
        __hip_atomic_fetch_add(gptr, 1u, __ATOMIC_RELAXED, __HIP_MEMORY_SCOPE_AGENT);
    }
  };

  // ---------------- layer 0 ----------------
  for (int t = 0; t < SEQn; t++){
    if (t) wait_phase((unsigned)t);
    step_body<NUMS, NUMS+Hn>(&sm,
        xp + (size_t)t*Bsz*NUMS,
        H0 + (size_t)t*Bsz*Hn,
        Wpk0, b0, cst,
        (unsigned int*)(H0 + (size_t)(t+1)*Bsz*Hn),
        mb, nb, w, l, tid);
    arrive();
  }

  // ---------------- layer 1 (pre-wait compute on A1 = h0_t) ----------------
  const int mf = w & 1, cgi = w >> 1;
  const int cgg = nb*4 + cgi;
  const int lrow = l & 15, lg = l >> 4;
  const int frow = mf*16 + lrow;

  for (int t = 0; t < SEQn; t++){
    const unsigned short* A1 = H0 + (size_t)(t+1)*Bsz*Hn;   // h0_t, stable
    const unsigned short* A2 = (t == 0) ? (H0 + (size_t)SEQn*Bsz*Hn)
                                        : (H1 + (size_t)((t-1)&1)*Bsz*Hn);
    // stage A1 chunks 0,1
    #pragma unroll
    for (int c = 0; c < 2; c++){
      for (int i = w; i < 32; i += 8){
        const int sIdx = i*64 + l;
        const int row = sIdx >> 6, uu = sIdx & 63, ku = uu ^ (row & 7);
        const unsigned short* src = A1 + (size_t)(mb*32 + row)*Hn + c*512 + ku*8;
        __builtin_amdgcn_global_load_lds(
          (const __attribute__((address_space(1))) void*)src,
          (__attribute__((address_space(3))) void*)&sm.a[c][i*512], 16, 0, 0);
      }
    }
    __syncthreads();   // A1 staged

    f32x4 acc = {0.f, 0.f, 0.f, 0.f};
    // MFMA chunks 0,1 BEFORE the wait (half the W stream off the critical path)
    #pragma unroll
    for (int c = 0; c < 2; c++){
      const unsigned short* wp = Wpk1 + ((size_t)(cgg*64 + c*16)*64 + l)*8;
      #pragma unroll
      for (int ks = 0; ks < 16; ks++){
        const int unit = ks*4 + lg;
        bf16x8 af = *(const bf16x8*)&sm.a[c][(frow*64 + (unit ^ (frow & 7)))*8];
        bf16x8 bw = *(const bf16x8*)(wp + (size_t)ks*512);
        acc = __builtin_amdgcn_mfma_f32_16x16x32_bf16(af, bw, acc, 0, 0, 0);
      }
    }

    wait_phase((unsigned)(SEQn + t));   // h1_{t-1} published; also fences sm.a reads

    // coherent loads of A2 = h1_prev (bypass L2; L3 has newest via write-through)
    unsigned long long rg[2][4][2];
    #pragma unroll
    for (int c = 0; c < 2; c++)
      #pragma unroll
      for (int j = 0; j < 4; j++){
        const int sIdx = j*512 + tid;
        const int row = sIdx >> 6, uu = sIdx & 63, ku = uu ^ (row & 7);
        const unsigned long long* qp = (const unsigned long long*)A2
            + ((size_t)(mb*32 + row)*Hn + c*512 + ku*8)/4;
        rg[c][j][0] = __hip_atomic_load(qp,   __ATOMIC_RELAXED, __HIP_MEMORY_SCOPE_AGENT);
        rg[c][j][1] = __hip_atomic_load(qp+1, __ATOMIC_RELAXED, __HIP_MEMORY_SCOPE_AGENT);
      }
    #pragma unroll
    for (int c = 0; c < 2; c++)
      #pragma unroll
      for (int j = 0; j < 4; j++){
        ulonglong2 v; v.x = rg[c][j][0]; v.y = rg[c][j][1];
        *(ulonglong2*)&sm.a[c][(j*512 + tid)*8] = v;
      }
    __syncthreads();   // A2 staged

    // MFMA chunks 2,3
    #pragma unroll
    for (int c = 0; c < 2; c++){
      const unsigned short* wp = Wpk1 + ((size_t)(cgg*64 + (2+c)*16)*64 + l)*8;
      #pragma unroll
      for (int ks = 0; ks < 16; ks++){
        const int unit = ks*4 + lg;
        bf16x8 af = *(const bf16x8*)&sm.a[c][(frow*64 + (unit ^ (frow & 7)))*8];
        bf16x8 bw = *(const bf16x8*)(wp + (size_t)ks*512);
        acc = __builtin_amdgcn_mfma_f32_16x16x32_bf16(af, bw, acc, 0, 0, 0);
      }
    }
    __syncthreads();   // sm.a reads done before e-alias write

    {
      const int jj = l & 15;
      #pragma unroll
      for (int r = 0; r < 4; r++){
        const int row = mf*16 + lg*4 + r;
        sm.e[(cgi*32 + row)*18 + jj] = acc[r];
      }
    }
    __syncthreads();
    epilogue2(&sm, b1, cst,
              (unsigned int*)(H1 + (size_t)(t & 1)*Bsz*Hn),
              (t == SEQn-1) ? hf : nullptr, mb, nb, tid);
    arrive();
  }
}

// ---- final FC + copy h,c to d_out ----
__global__ __launch_bounds__(256)
void fc_out_kernel(const float* __restrict__ hf, const float* __restrict__ cst,
                   const float* __restrict__ fcw, const float* __restrict__ fcb,
                   float* __restrict__ dout){
  __shared__ float hrow[Hn];
  const int b = blockIdx.x, tid = threadIdx.x;
  for (int i = tid; i < Hn; i += 256) hrow[i] = hf[(size_t)b*Hn + i];
  __syncthreads();
  if (tid < PRED){
    float a = fcb[tid];
    for (int k = 0; k < Hn; k++) a += hrow[k] * fcw[(size_t)k*PRED + tid];
    dout[(size_t)b*PRED + tid] = tanhf(a);
  }
  for (int i = tid; i < Hn; i += 256){
    dout[Bsz*PRED + (size_t)b*Hn + i] = hf[(size_t)b*Hn + i];
    dout[Bsz*PRED + (size_t)Bsz*Hn + (size_t)b*Hn + i] = cst[(size_t)b*Hn + i];
  }
}

extern "C" void kernel_launch(void* const* d_in, const int* in_sizes, int n_in,
                              void* d_out, int out_size, void* d_ws, size_t ws_size,
                              hipStream_t stream){
  const float* x   = (const float*)d_in[0];
  const float* W0  = (const float*)d_in[1];
  const float* b0  = (const float*)d_in[2];
  const float* W1  = (const float*)d_in[3];
  const float* b1  = (const float*)d_in[4];
  const float* fcw = (const float*)d_in[5];
  const float* fcb = (const float*)d_in[6];
  float* dout = (float*)d_out;

  char* p = (char*)d_ws;
  auto alloc = [&](size_t bytes)->void*{
    void* r = (void*)p; p += (bytes + 255) & ~(size_t)255; return r;
  };
  unsigned short* xp   = (unsigned short*)alloc((size_t)SEQn*Bsz*NUMS*2);
  unsigned short* Wpk0 = (unsigned short*)alloc((size_t)256*36*64*8*2);
  unsigned short* Wpk1 = (unsigned short*)alloc((size_t)256*64*64*8*2);
  unsigned short* H0   = (unsigned short*)alloc((size_t)(SEQn+1)*Bsz*Hn*2);
  unsigned short* H1   = (unsigned short*)alloc((size_t)2*Bsz*Hn*2);
  float* cst = (float*)alloc((size_t)Bsz*Hn*4);
  float* hf  = (float*)alloc((size_t)Bsz*Hn*4);
  unsigned int* ctrA = (unsigned int*)alloc(1024*4);   // 4 mb x 8 groups x 32 uints
  unsigned int* gctr = (unsigned int*)alloc(256*4);    // 4 mb x 64 uints

  pack_x_kernel<<<dim3(SEQn/64, NUMS/64, Bsz), dim3(256), 0, stream>>>(x, xp);
  pack_w_kernel<<<dim3((256*36*64 + 255)/256), dim3(256), 0, stream>>>(W0, Wpk0, 36);
  pack_w_kernel<<<dim3((256*64*64 + 255)/256), dim3(256), 0, stream>>>(W1, Wpk1, 64);
  zero_kernel<<<dim3((Bsz*Hn + 255)/256), dim3(256), 0, stream>>>(H0, cst, ctrA);

  lstm_persist<<<dim3(256), dim3(512), 0, stream>>>(
      xp, H0, H1, Wpk0, Wpk1, b0, b1, cst, hf, ctrA, gctr);

  fc_out_kernel<<<dim3(Bsz), dim3(256), 0, stream>>>(hf, cst, fcw, fcb, dout);
}